// Round 4
// baseline (722.142 us; speedup 1.0000x reference)
//
#include <hip/hip_runtime.h>

// ---------------- CSR build ----------------

__global__ __launch_bounds__(256) void k_hist(const int* __restrict__ dst, int E,
                                              int* __restrict__ degcnt) {
    int i = blockIdx.x * 256 + threadIdx.x;
    if (i < E) atomicAdd(&degcnt[dst[i]], 1);
}

__global__ __launch_bounds__(256) void k_deg_finalize(const int* __restrict__ degcnt,
                                                      float* __restrict__ invsqrt,
                                                      int* __restrict__ blocksums, int N) {
    __shared__ int sd[256];
    int t = threadIdx.x;
    int i = blockIdx.x * 256 + t;
    int v = (i < N) ? degcnt[i] : 0;
    if (i < N) invsqrt[i] = rsqrtf((float)(v + 1));   // +1: self-loop
    sd[t] = v;
    __syncthreads();
#pragma unroll
    for (int s = 128; s > 0; s >>= 1) {
        if (t < s) sd[t] += sd[t + s];
        __syncthreads();
    }
    if (t == 0) blocksums[blockIdx.x] = sd[0];
}

__global__ __launch_bounds__(1024) void k_scan_blocks(int* blocksums, int NB) {
    __shared__ int s[1024];
    int t = threadIdx.x;
    int v = (t < NB) ? blocksums[t] : 0;
    s[t] = v;
    __syncthreads();
    for (int off = 1; off < 1024; off <<= 1) {
        int x = (t >= off) ? s[t - off] : 0;
        __syncthreads();
        s[t] += x;
        __syncthreads();
    }
    if (t < NB) blocksums[t] = s[t] - v;   // exclusive
}

__global__ __launch_bounds__(256) void k_rowstart(const int* __restrict__ degcnt,
                                                  const int* __restrict__ blocksums,
                                                  int* __restrict__ rowstart,
                                                  int* __restrict__ rowwork, int N, int E) {
    __shared__ int s[256];
    int t = threadIdx.x;
    int i = blockIdx.x * 256 + t;
    int v = (i < N) ? degcnt[i] : 0;
    s[t] = v;
    __syncthreads();
    for (int off = 1; off < 256; off <<= 1) {
        int x = (t >= off) ? s[t - off] : 0;
        __syncthreads();
        s[t] += x;
        __syncthreads();
    }
    if (i < N) {
        int e = s[t] - v + blocksums[blockIdx.x];
        rowstart[i] = e;
        rowwork[i] = e;
    }
    if (blockIdx.x == 0 && t == 0) rowstart[N] = E;
}

__global__ __launch_bounds__(256) void k_fill(const int* __restrict__ src,
                                              const int* __restrict__ dst, int E,
                                              const float* __restrict__ invsqrt,
                                              int* __restrict__ rowwork,
                                              int* __restrict__ csr_src,
                                              float* __restrict__ csr_w) {
    int i = blockIdx.x * 256 + threadIdx.x;
    if (i < E) {
        int s = src[i], d = dst[i];
        int pos = atomicAdd(&rowwork[d], 1);
        csr_src[pos] = s;
        csr_w[pos] = invsqrt[s];
    }
}

// ---------------- GEMM common geometry ----------------
// 256 threads, tile 128 rows x 128 cols, per-thread 8x8 acc.
// rg = t>>4 (row group: rows rg*8..rg*8+7), cg = t&15 (cols cg*8..cg*8+7).
// LDS: xs_t[KT=32][136] k-major (b128 reads of 8 consecutive rows),
//      ws [KT=32][136] k-major (b128 reads of 8 consecutive cols).
// stride 136 floats = 544 B keeps 16B alignment for all kk.

#define GSTRIDE 136

// ---------------- GEMM1: x[N,256] @ W[256,128] -> out[N,128] ----------------

__global__ __launch_bounds__(256) void k_gemm1(const float* __restrict__ x,
                                               const float* __restrict__ W,
                                               float* __restrict__ out, int N) {
    __shared__ __align__(16) float xs_t[32][GSTRIDE];
    __shared__ __align__(16) float ws[32][GSTRIDE];
    int t = threadIdx.x;
    int rg = t >> 4;
    int cg = t & 15;
    int row0 = blockIdx.x * 128;
    float acc[8][8];
#pragma unroll
    for (int a = 0; a < 8; a++)
#pragma unroll
        for (int b = 0; b < 8; b++) acc[a][b] = 0.f;

    for (int k0 = 0; k0 < 256; k0 += 32) {
        // stage x tile: 128 rows x 32 k, transposed into xs_t[k][row]
#pragma unroll
        for (int l = 0; l < 4; l++) {
            int idx = t + 256 * l;
            int rr = idx >> 3, kq = idx & 7;
            int grow = row0 + rr;
            float4 v = make_float4(0.f, 0.f, 0.f, 0.f);
            if (grow < N) v = *(const float4*)(x + (size_t)grow * 256 + k0 + kq * 4);
            xs_t[kq * 4 + 0][rr] = v.x;
            xs_t[kq * 4 + 1][rr] = v.y;
            xs_t[kq * 4 + 2][rr] = v.z;
            xs_t[kq * 4 + 3][rr] = v.w;
        }
        // stage W tile: 32 k x 128 cols
#pragma unroll
        for (int l = 0; l < 4; l++) {
            int idx = t + 256 * l;
            int kr = idx >> 5, cq = idx & 31;
            *(float4*)&ws[kr][cq * 4] = *(const float4*)(W + (size_t)(k0 + kr) * 128 + cq * 4);
        }
        __syncthreads();
#pragma unroll
        for (int kk = 0; kk < 32; kk++) {
            float4 xa0 = *(float4*)&xs_t[kk][rg * 8];
            float4 xa1 = *(float4*)&xs_t[kk][rg * 8 + 4];
            float4 wb0 = *(float4*)&ws[kk][cg * 8];
            float4 wb1 = *(float4*)&ws[kk][cg * 8 + 4];
            float xa[8] = {xa0.x, xa0.y, xa0.z, xa0.w, xa1.x, xa1.y, xa1.z, xa1.w};
            float wb[8] = {wb0.x, wb0.y, wb0.z, wb0.w, wb1.x, wb1.y, wb1.z, wb1.w};
#pragma unroll
            for (int i = 0; i < 8; i++)
#pragma unroll
                for (int j = 0; j < 8; j++) acc[i][j] = fmaf(xa[i], wb[j], acc[i][j]);
        }
        __syncthreads();
    }
#pragma unroll
    for (int i = 0; i < 8; i++) {
        int grow = row0 + rg * 8 + i;
        if (grow < N) {
            float4 v0 = make_float4(acc[i][0], acc[i][1], acc[i][2], acc[i][3]);
            float4 v1 = make_float4(acc[i][4], acc[i][5], acc[i][6], acc[i][7]);
            *(float4*)(out + (size_t)grow * 128 + cg * 8) = v0;
            *(float4*)(out + (size_t)grow * 128 + cg * 8 + 4) = v1;
        }
    }
}

// ---------------- GEMM2: G[N,128] @ [Wmu|Wls][128,128] + bias -> mu, ls ----------------

__global__ __launch_bounds__(256) void k_gemm2(const float* __restrict__ G,
                                               const float* __restrict__ Wmu,
                                               const float* __restrict__ bmu,
                                               const float* __restrict__ Wls,
                                               const float* __restrict__ bls,
                                               float* __restrict__ omu,
                                               float* __restrict__ ols, int N) {
    __shared__ __align__(16) float xs_t[32][GSTRIDE];
    __shared__ __align__(16) float ws[32][GSTRIDE];
    int t = threadIdx.x;
    int rg = t >> 4;
    int cg = t & 15;
    int row0 = blockIdx.x * 128;
    float acc[8][8];
#pragma unroll
    for (int a = 0; a < 8; a++)
#pragma unroll
        for (int b = 0; b < 8; b++) acc[a][b] = 0.f;

    for (int k0 = 0; k0 < 128; k0 += 32) {
#pragma unroll
        for (int l = 0; l < 4; l++) {
            int idx = t + 256 * l;
            int rr = idx >> 3, kq = idx & 7;
            int grow = row0 + rr;
            float4 v = make_float4(0.f, 0.f, 0.f, 0.f);
            if (grow < N) v = *(const float4*)(G + (size_t)grow * 128 + k0 + kq * 4);
            xs_t[kq * 4 + 0][rr] = v.x;
            xs_t[kq * 4 + 1][rr] = v.y;
            xs_t[kq * 4 + 2][rr] = v.z;
            xs_t[kq * 4 + 3][rr] = v.w;
        }
#pragma unroll
        for (int l = 0; l < 4; l++) {
            int idx = t + 256 * l;
            int kr = idx >> 5, cq = idx & 31;
            const float* wp = (cq < 16) ? (Wmu + (size_t)(k0 + kr) * 64 + cq * 4)
                                        : (Wls + (size_t)(k0 + kr) * 64 + (cq - 16) * 4);
            *(float4*)&ws[kr][cq * 4] = *(const float4*)wp;
        }
        __syncthreads();
#pragma unroll
        for (int kk = 0; kk < 32; kk++) {
            float4 xa0 = *(float4*)&xs_t[kk][rg * 8];
            float4 xa1 = *(float4*)&xs_t[kk][rg * 8 + 4];
            float4 wb0 = *(float4*)&ws[kk][cg * 8];
            float4 wb1 = *(float4*)&ws[kk][cg * 8 + 4];
            float xa[8] = {xa0.x, xa0.y, xa0.z, xa0.w, xa1.x, xa1.y, xa1.z, xa1.w};
            float wb[8] = {wb0.x, wb0.y, wb0.z, wb0.w, wb1.x, wb1.y, wb1.z, wb1.w};
#pragma unroll
            for (int i = 0; i < 8; i++)
#pragma unroll
                for (int j = 0; j < 8; j++) acc[i][j] = fmaf(xa[i], wb[j], acc[i][j]);
        }
        __syncthreads();
    }
    // cols cg*8..cg*8+7: cg<8 -> mu cols cg*8..; cg>=8 -> ls cols (cg-8)*8..
    int is_mu = (cg < 8);
    int ccol = (is_mu ? cg : cg - 8) * 8;
    const float* bp = is_mu ? (bmu + ccol) : (bls + ccol);
    float* ob = is_mu ? omu : ols;
    float4 b0 = *(const float4*)bp;
    float4 b1 = *(const float4*)(bp + 4);
#pragma unroll
    for (int i = 0; i < 8; i++) {
        int grow = row0 + rg * 8 + i;
        if (grow < N) {
            float4 v0 = make_float4(acc[i][0] + b0.x, acc[i][1] + b0.y,
                                    acc[i][2] + b0.z, acc[i][3] + b0.w);
            float4 v1 = make_float4(acc[i][4] + b1.x, acc[i][5] + b1.y,
                                    acc[i][6] + b1.z, acc[i][7] + b1.w);
            *(float4*)(ob + (size_t)grow * 64 + ccol) = v0;
            *(float4*)(ob + (size_t)grow * 64 + ccol + 4) = v1;
        }
    }
}

// ---------------- Aggregation: out[i] = isq_i*(sum_e w_e*in[s_e] + isq_i*in[i]) ----------------

template <int RELU>
__global__ __launch_bounds__(128) void k_agg(const float* __restrict__ in,
                                             const float* __restrict__ invsqrt,
                                             const int* __restrict__ rowstart,
                                             const int* __restrict__ csr_src,
                                             const float* __restrict__ csr_w,
                                             const float* __restrict__ bias,
                                             float* __restrict__ out, int N) {
    int i = blockIdx.x;
    int f = threadIdx.x;   // feature 0..127
    __shared__ int s_src[128];
    __shared__ float s_w[128];
    int start = rowstart[i], end = rowstart[i + 1];
    float isq = invsqrt[i];
    float acc = isq * in[(size_t)i * 128 + f];   // self-loop (norm isq^2, outer isq at end)
    for (int base = start; base < end; base += 128) {
        int cnt = min(128, end - base);
        if (f < cnt) {
            s_src[f] = csr_src[base + f];
            s_w[f] = csr_w[base + f];
        }
        __syncthreads();
        int j = 0;
        for (; j + 4 <= cnt; j += 4) {
            int s0 = s_src[j], s1 = s_src[j + 1], s2 = s_src[j + 2], s3 = s_src[j + 3];
            float w0 = s_w[j], w1 = s_w[j + 1], w2 = s_w[j + 2], w3 = s_w[j + 3];
            float a0 = in[(size_t)s0 * 128 + f];
            float a1 = in[(size_t)s1 * 128 + f];
            float a2 = in[(size_t)s2 * 128 + f];
            float a3 = in[(size_t)s3 * 128 + f];
            acc = fmaf(w0, a0, acc);
            acc = fmaf(w1, a1, acc);
            acc = fmaf(w2, a2, acc);
            acc = fmaf(w3, a3, acc);
        }
        for (; j < cnt; j++) acc = fmaf(s_w[j], in[(size_t)s_src[j] * 128 + f], acc);
        __syncthreads();
    }
    float rv = isq * acc;
    if (RELU) {
        rv += bias[f];
        rv = fmaxf(rv, 0.f);
    }
    out[(size_t)i * 128 + f] = rv;
}

// ---------------- launch ----------------

extern "C" void kernel_launch(void* const* d_in, const int* in_sizes, int n_in,
                              void* d_out, int out_size, void* d_ws, size_t ws_size,
                              hipStream_t stream) {
    const float* x   = (const float*)d_in[0];
    const int*   ei  = (const int*)d_in[1];
    const float* W1  = (const float*)d_in[2];
    const float* b1  = (const float*)d_in[3];
    const float* Wmu = (const float*)d_in[4];
    const float* bmu = (const float*)d_in[5];
    const float* Wls = (const float*)d_in[6];
    const float* bls = (const float*)d_in[7];

    int N = in_sizes[0] / 256;
    int E = in_sizes[1] / 2;
    const int* src = ei;
    const int* dst = ei + E;
    float* omu = (float*)d_out;
    float* ols = omu + (size_t)N * 64;

    char* w = (char*)d_ws;
    size_t off = 0;
    auto alloc = [&](size_t bytes) -> char* {
        char* p = w + off;
        off = (off + bytes + 255) & ~(size_t)255;
        return p;
    };
    int*   degcnt    = (int*)alloc((size_t)N * 4);
    float* invsqrt   = (float*)alloc((size_t)N * 4);
    int*   rowstart  = (int*)alloc((size_t)(N + 1) * 4);
    int*   rowwork   = (int*)alloc((size_t)N * 4);
    int*   blocksums = (int*)alloc(4096);
    int*   csr_src   = (int*)alloc((size_t)E * 4);
    float* csr_w     = (float*)alloc((size_t)E * 4);
    float* bufA      = (float*)alloc((size_t)N * 128 * 4);   // H1, later G2
    float* bufB      = (float*)alloc((size_t)N * 128 * 4);   // h = relu(...)

    int NB = (N + 255) / 256;

    hipMemsetAsync(degcnt, 0, (size_t)N * 4, stream);
    k_hist<<<(E + 255) / 256, 256, 0, stream>>>(dst, E, degcnt);
    k_deg_finalize<<<NB, 256, 0, stream>>>(degcnt, invsqrt, blocksums, N);
    k_scan_blocks<<<1, 1024, 0, stream>>>(blocksums, NB);
    k_rowstart<<<NB, 256, 0, stream>>>(degcnt, blocksums, rowstart, rowwork, N, E);
    k_fill<<<(E + 255) / 256, 256, 0, stream>>>(src, dst, E, invsqrt, rowwork, csr_src, csr_w);

    k_gemm1<<<(N + 127) / 128, 256, 0, stream>>>(x, W1, bufA, N);
    k_agg<1><<<N, 128, 0, stream>>>(bufA, invsqrt, rowstart, csr_src, csr_w, b1, bufB, N);
    k_agg<0><<<N, 128, 0, stream>>>(bufB, invsqrt, rowstart, csr_src, csr_w, nullptr, bufA, N);
    k_gemm2<<<(N + 127) / 128, 256, 0, stream>>>(bufA, Wmu, bmu, Wls, bls, omu, ols, N);
}

// Round 7
// 574.645 us; speedup vs baseline: 1.2567x; 1.2567x over previous
//
#include <hip/hip_runtime.h>
#include <hip/hip_fp16.h>

// ---------------- f16x2 pack/unpack ----------------

__device__ __forceinline__ unsigned int pack_h2(float a, float b) {
    __half2 h = __floats2half2_rn(a, b);
    return *reinterpret_cast<unsigned int*>(&h);
}
__device__ __forceinline__ float2 unpack_h2(unsigned int u) {
    __half2 h = *reinterpret_cast<__half2*>(&u);
    return __half22float2(h);
}

// ---------------- CSR build ----------------

__global__ __launch_bounds__(256) void k_hist(const int* __restrict__ dst, int E,
                                              int* __restrict__ degcnt) {
    int i = blockIdx.x * 256 + threadIdx.x;
    if (i < E) atomicAdd(&degcnt[dst[i]], 1);
}

__global__ __launch_bounds__(256) void k_deg_finalize(const int* __restrict__ degcnt,
                                                      float* __restrict__ invsqrt,
                                                      int* __restrict__ blocksums, int N) {
    __shared__ int sd[256];
    int t = threadIdx.x;
    int i = blockIdx.x * 256 + t;
    int v = (i < N) ? degcnt[i] : 0;
    if (i < N) invsqrt[i] = rsqrtf((float)(v + 1));   // +1: self-loop
    sd[t] = v;
    __syncthreads();
#pragma unroll
    for (int s = 128; s > 0; s >>= 1) {
        if (t < s) sd[t] += sd[t + s];
        __syncthreads();
    }
    if (t == 0) blocksums[blockIdx.x] = sd[0];
}

__global__ __launch_bounds__(1024) void k_scan_blocks(int* blocksums, int NB) {
    __shared__ int s[1024];
    int t = threadIdx.x;
    int v = (t < NB) ? blocksums[t] : 0;
    s[t] = v;
    __syncthreads();
    for (int off = 1; off < 1024; off <<= 1) {
        int x = (t >= off) ? s[t - off] : 0;
        __syncthreads();
        s[t] += x;
        __syncthreads();
    }
    if (t < NB) blocksums[t] = s[t] - v;   // exclusive
}

__global__ __launch_bounds__(256) void k_rowstart(const int* __restrict__ degcnt,
                                                  const int* __restrict__ blocksums,
                                                  int* __restrict__ rowstart,
                                                  int* __restrict__ rowwork, int N, int E) {
    __shared__ int s[256];
    int t = threadIdx.x;
    int i = blockIdx.x * 256 + t;
    int v = (i < N) ? degcnt[i] : 0;
    s[t] = v;
    __syncthreads();
    for (int off = 1; off < 256; off <<= 1) {
        int x = (t >= off) ? s[t - off] : 0;
        __syncthreads();
        s[t] += x;
        __syncthreads();
    }
    if (i < N) {
        int e = s[t] - v + blocksums[blockIdx.x];
        rowstart[i] = e;
        rowwork[i] = e;
    }
    if (blockIdx.x == 0 && t == 0) rowstart[N] = E;
}

__global__ __launch_bounds__(256) void k_fill(const int* __restrict__ src,
                                              const int* __restrict__ dst, int E,
                                              const float* __restrict__ invsqrt,
                                              int* __restrict__ rowwork,
                                              uint2* __restrict__ csr_sw) {
    int i = blockIdx.x * 256 + threadIdx.x;
    if (i < E) {
        int s = src[i], d = dst[i];
        int pos = atomicAdd(&rowwork[d], 1);
        csr_sw[pos] = make_uint2((unsigned int)s, __float_as_uint(invsqrt[s]));
    }
}

// ---------------- GEMM geometry ----------------
// 256 threads, tile 64 rows x 128 cols, per-thread 4 rows x 8 cols.
// rg = t>>4 (rows rg*4..+3), cg = t&15 (logical cols cg*8..+7).
// xs[64][44] row-major f32 (stride 44: xa b32 reads are 2-way -> free;
//   staging b128 writes hit the structural 8-sweep minimum).
// ws[32][140] col-swizzled: logical float4-col cq stored at 4*cq + 4*(cq>>3);
//   wb b128 reads land exactly 2 addrs per bank position (structural min).

#define XS_S 44
#define WS_S 140
__device__ __forceinline__ int ws_phys4(int cq) { return cq * 4 + (cq >> 3) * 4; }
__device__ __forceinline__ int ws_o(int cg) { return cg * 8 + (cg >> 2) * 4; }

// ---------------- GEMM1: x[N,256] @ W1[256,128] -> H1 f16x2 table [N][64] ----------------

__global__ __launch_bounds__(256, 4) void k_gemm1(const float* __restrict__ x,
                                                  const float* __restrict__ W,
                                                  unsigned int* __restrict__ H1, int N) {
    __shared__ __align__(16) float xs[64][XS_S];
    __shared__ __align__(16) float ws[32][WS_S];
    int t = threadIdx.x;
    int rg = t >> 4;
    int cg = t & 15;
    int row0 = blockIdx.x * 64;
    int o4 = ws_o(cg);
    float acc[4][8];
#pragma unroll
    for (int a = 0; a < 4; a++)
#pragma unroll
        for (int b = 0; b < 8; b++) acc[a][b] = 0.f;

    for (int k0 = 0; k0 < 256; k0 += 32) {
        // stage x: 64 rows x 32 k = 512 float4, 2 per thread
#pragma unroll
        for (int l = 0; l < 2; l++) {
            int idx = t + 256 * l;
            int rr = idx >> 3, kq = idx & 7;
            int grow = row0 + rr;
            float4 v = make_float4(0.f, 0.f, 0.f, 0.f);
            if (grow < N) v = *(const float4*)(x + (size_t)grow * 256 + k0 + kq * 4);
            *(float4*)&xs[rr][kq * 4] = v;
        }
        // stage W: 32 k x 128 cols = 1024 float4, 4 per thread (swizzled cols)
#pragma unroll
        for (int l = 0; l < 4; l++) {
            int idx = t + 256 * l;
            int kr = idx >> 5, cq = idx & 31;
            *(float4*)&ws[kr][ws_phys4(cq)] = *(const float4*)(W + (size_t)(k0 + kr) * 128 + cq * 4);
        }
        __syncthreads();
#pragma unroll
        for (int kk = 0; kk < 32; kk++) {
            float4 wb0 = *(float4*)&ws[kk][o4];
            float4 wb1 = *(float4*)&ws[kk][o4 + 4];
            float wb[8] = {wb0.x, wb0.y, wb0.z, wb0.w, wb1.x, wb1.y, wb1.z, wb1.w};
            float xa[4];
#pragma unroll
            for (int i = 0; i < 4; i++) xa[i] = xs[rg * 4 + i][kk];
#pragma unroll
            for (int i = 0; i < 4; i++)
#pragma unroll
                for (int j = 0; j < 8; j++) acc[i][j] = fmaf(xa[i], wb[j], acc[i][j]);
        }
        __syncthreads();
    }
#pragma unroll
    for (int i = 0; i < 4; i++) {
        int grow = row0 + rg * 4 + i;
        if (grow < N) {
            uint4 st;
            st.x = pack_h2(acc[i][0], acc[i][1]);
            st.y = pack_h2(acc[i][2], acc[i][3]);
            st.z = pack_h2(acc[i][4], acc[i][5]);
            st.w = pack_h2(acc[i][6], acc[i][7]);
            *(uint4*)(H1 + (size_t)grow * 64 + cg * 4) = st;
        }
    }
}

// ---------------- GEMM2: G2[N,128] @ [Wmu|Wls][128,128] + bias -> mu, ls (f32) ----------------

__global__ __launch_bounds__(256, 4) void k_gemm2(const float* __restrict__ G,
                                                  const float* __restrict__ Wmu,
                                                  const float* __restrict__ bmu,
                                                  const float* __restrict__ Wls,
                                                  const float* __restrict__ bls,
                                                  float* __restrict__ omu,
                                                  float* __restrict__ ols, int N) {
    __shared__ __align__(16) float xs[64][XS_S];
    __shared__ __align__(16) float ws[32][WS_S];
    int t = threadIdx.x;
    int rg = t >> 4;
    int cg = t & 15;
    int row0 = blockIdx.x * 64;
    int o4 = ws_o(cg);
    float acc[4][8];
#pragma unroll
    for (int a = 0; a < 4; a++)
#pragma unroll
        for (int b = 0; b < 8; b++) acc[a][b] = 0.f;

    for (int k0 = 0; k0 < 128; k0 += 32) {
#pragma unroll
        for (int l = 0; l < 2; l++) {
            int idx = t + 256 * l;
            int rr = idx >> 3, kq = idx & 7;
            int grow = row0 + rr;
            float4 v = make_float4(0.f, 0.f, 0.f, 0.f);
            if (grow < N) v = *(const float4*)(G + (size_t)grow * 128 + k0 + kq * 4);
            *(float4*)&xs[rr][kq * 4] = v;
        }
#pragma unroll
        for (int l = 0; l < 4; l++) {
            int idx = t + 256 * l;
            int kr = idx >> 5, cq = idx & 31;
            const float* wp = (cq < 16) ? (Wmu + (size_t)(k0 + kr) * 64 + cq * 4)
                                        : (Wls + (size_t)(k0 + kr) * 64 + (cq - 16) * 4);
            *(float4*)&ws[kr][ws_phys4(cq)] = *(const float4*)wp;
        }
        __syncthreads();
#pragma unroll
        for (int kk = 0; kk < 32; kk++) {
            float4 wb0 = *(float4*)&ws[kk][o4];
            float4 wb1 = *(float4*)&ws[kk][o4 + 4];
            float wb[8] = {wb0.x, wb0.y, wb0.z, wb0.w, wb1.x, wb1.y, wb1.z, wb1.w};
            float xa[4];
#pragma unroll
            for (int i = 0; i < 4; i++) xa[i] = xs[rg * 4 + i][kk];
#pragma unroll
            for (int i = 0; i < 4; i++)
#pragma unroll
                for (int j = 0; j < 8; j++) acc[i][j] = fmaf(xa[i], wb[j], acc[i][j]);
        }
        __syncthreads();
    }
    int is_mu = (cg < 8);
    int ccol = (is_mu ? cg : cg - 8) * 8;
    const float* bp = is_mu ? (bmu + ccol) : (bls + ccol);
    float* ob = is_mu ? omu : ols;
    float4 b0 = *(const float4*)bp;
    float4 b1 = *(const float4*)(bp + 4);
#pragma unroll
    for (int i = 0; i < 4; i++) {
        int grow = row0 + rg * 4 + i;
        if (grow < N) {
            float4 v0 = make_float4(acc[i][0] + b0.x, acc[i][1] + b0.y,
                                    acc[i][2] + b0.z, acc[i][3] + b0.w);
            float4 v1 = make_float4(acc[i][4] + b1.x, acc[i][5] + b1.y,
                                    acc[i][6] + b1.z, acc[i][7] + b1.w);
            *(float4*)(ob + (size_t)grow * 64 + ccol) = v0;
            *(float4*)(ob + (size_t)grow * 64 + ccol + 4) = v1;
        }
    }
}

// ---------------- Aggregation over f16x2 table ----------------
// out[i] = isq_i*(sum_e w_e*tbl[s_e] + isq_i*tbl[i]); MODE1: +bias, relu, f16 out; MODE0: f32 out.
// 1 wave per node, thread t <-> feature pair (2t, 2t+1). Edge (src,w) broadcast via shfl.

template <int MODE>
__global__ __launch_bounds__(256, 8) void k_agg(const unsigned int* __restrict__ tbl,
                                                const float* __restrict__ invsqrt,
                                                const int* __restrict__ rowstart,
                                                const uint2* __restrict__ csr,
                                                const float* __restrict__ bias,
                                                unsigned int* __restrict__ out16,
                                                float2* __restrict__ out32, int N) {
    int node = blockIdx.x * 4 + (threadIdx.x >> 6);
    int t = threadIdx.x & 63;
    if (node >= N) return;
    int start = rowstart[node], end = rowstart[node + 1];
    float isq = invsqrt[node];
    float2 v = unpack_h2(tbl[(size_t)node * 64 + t]);
    float aL = isq * v.x, aH = isq * v.y;   // self term (outer isq applied at end)
    for (int base = start; base < end; base += 64) {
        int cnt = end - base;
        if (cnt > 64) cnt = 64;
        uint2 e = make_uint2(0u, 0u);
        if (t < cnt) e = csr[base + t];
        int j = 0;
        for (; j + 2 <= cnt; j += 2) {
            int s0 = __shfl((int)e.x, j);
            float w0 = __int_as_float(__shfl((int)e.y, j));
            int s1 = __shfl((int)e.x, j + 1);
            float w1 = __int_as_float(__shfl((int)e.y, j + 1));
            float2 f0 = unpack_h2(tbl[(size_t)s0 * 64 + t]);
            float2 f1 = unpack_h2(tbl[(size_t)s1 * 64 + t]);
            aL = fmaf(w0, f0.x, aL);
            aH = fmaf(w0, f0.y, aH);
            aL = fmaf(w1, f1.x, aL);
            aH = fmaf(w1, f1.y, aH);
        }
        if (j < cnt) {
            int s0 = __shfl((int)e.x, j);
            float w0 = __int_as_float(__shfl((int)e.y, j));
            float2 f0 = unpack_h2(tbl[(size_t)s0 * 64 + t]);
            aL = fmaf(w0, f0.x, aL);
            aH = fmaf(w0, f0.y, aH);
        }
    }
    aL *= isq;
    aH *= isq;
    if (MODE == 1) {
        float2 b = ((const float2*)bias)[t];
        aL = fmaxf(aL + b.x, 0.f);
        aH = fmaxf(aH + b.y, 0.f);
        out16[(size_t)node * 64 + t] = pack_h2(aL, aH);
    } else {
        out32[(size_t)node * 64 + t] = make_float2(aL, aH);
    }
}

// ---------------- launch ----------------

extern "C" void kernel_launch(void* const* d_in, const int* in_sizes, int n_in,
                              void* d_out, int out_size, void* d_ws, size_t ws_size,
                              hipStream_t stream) {
    const float* x   = (const float*)d_in[0];
    const int*   ei  = (const int*)d_in[1];
    const float* W1  = (const float*)d_in[2];
    const float* b1  = (const float*)d_in[3];
    const float* Wmu = (const float*)d_in[4];
    const float* bmu = (const float*)d_in[5];
    const float* Wls = (const float*)d_in[6];
    const float* bls = (const float*)d_in[7];

    int N = in_sizes[0] / 256;
    int E = in_sizes[1] / 2;
    const int* src = ei;
    const int* dst = ei + E;
    float* omu = (float*)d_out;
    float* ols = omu + (size_t)N * 64;

    char* w = (char*)d_ws;
    size_t off = 0;
    auto alloc = [&](size_t bytes) -> char* {
        char* p = w + off;
        off = (off + bytes + 255) & ~(size_t)255;
        return p;
    };
    int*          degcnt    = (int*)alloc((size_t)N * 4);
    float*        invsqrt   = (float*)alloc((size_t)N * 4);
    int*          rowstart  = (int*)alloc((size_t)(N + 1) * 4);
    int*          rowwork   = (int*)alloc((size_t)N * 4);
    int*          blocksums = (int*)alloc(4096);
    uint2*        csr_sw    = (uint2*)alloc((size_t)E * 8);
    unsigned int* H1f16     = (unsigned int*)alloc((size_t)N * 64 * 4);  // x@W1, f16x2
    unsigned int* Hf16      = (unsigned int*)alloc((size_t)N * 64 * 4);  // relu(agg1), f16x2
    float*        G2        = (float*)alloc((size_t)N * 128 * 4);        // agg2 out, f32

    int NB = (N + 255) / 256;

    hipMemsetAsync(degcnt, 0, (size_t)N * 4, stream);
    k_hist<<<(E + 255) / 256, 256, 0, stream>>>(dst, E, degcnt);
    k_deg_finalize<<<NB, 256, 0, stream>>>(degcnt, invsqrt, blocksums, N);
    k_scan_blocks<<<1, 1024, 0, stream>>>(blocksums, NB);
    k_rowstart<<<NB, 256, 0, stream>>>(degcnt, blocksums, rowstart, rowwork, N, E);
    k_fill<<<(E + 255) / 256, 256, 0, stream>>>(src, dst, E, invsqrt, rowwork, csr_sw);

    k_gemm1<<<(N + 63) / 64, 256, 0, stream>>>(x, W1, H1f16, N);
    k_agg<1><<<(N + 3) / 4, 256, 0, stream>>>(H1f16, invsqrt, rowstart, csr_sw, b1,
                                              Hf16, nullptr, N);
    k_agg<0><<<(N + 3) / 4, 256, 0, stream>>>(Hf16, invsqrt, rowstart, csr_sw, nullptr,
                                              nullptr, (float2*)G2, N);
    k_gemm2<<<(N + 63) / 64, 256, 0, stream>>>(G2, Wmu, bmu, Wls, bls, omu, ols, N);
}

// Round 8
// 557.925 us; speedup vs baseline: 1.2943x; 1.0300x over previous
//
#include <hip/hip_runtime.h>
#include <hip/hip_fp16.h>

typedef short bf16x8 __attribute__((ext_vector_type(8)));
typedef float f32x4 __attribute__((ext_vector_type(4)));

// ---------------- conversions ----------------

__device__ __forceinline__ unsigned int pack_h2(float a, float b) {
    __half2 h = __floats2half2_rn(a, b);
    return *reinterpret_cast<unsigned int*>(&h);
}
__device__ __forceinline__ float2 unpack_h2(unsigned int u) {
    __half2 h = *reinterpret_cast<__half2*>(&u);
    return __half22float2(h);
}
__device__ __forceinline__ unsigned short f2bf(float f) {   // RNE f32->bf16 bits
    unsigned int u = __float_as_uint(f);
    unsigned int r = (u + 0x7FFFu + ((u >> 16) & 1u)) >> 16;
    return (unsigned short)r;
}
__device__ __forceinline__ float bf2f(unsigned short h) {
    return __uint_as_float((unsigned int)h << 16);
}
__device__ __forceinline__ unsigned short f2h_bits(float f) {
    __half h = __float2half_rn(f);
    return *reinterpret_cast<unsigned short*>(&h);
}

// ---------------- CSR build ----------------

__global__ __launch_bounds__(256) void k_hist(const int* __restrict__ dst, int E,
                                              int* __restrict__ degcnt) {
    int i = blockIdx.x * 256 + threadIdx.x;
    if (i < E) atomicAdd(&degcnt[dst[i]], 1);
}

__global__ __launch_bounds__(256) void k_deg_finalize(const int* __restrict__ degcnt,
                                                      float* __restrict__ invsqrt,
                                                      int* __restrict__ blocksums, int N) {
    __shared__ int sd[256];
    int t = threadIdx.x;
    int i = blockIdx.x * 256 + t;
    int v = (i < N) ? degcnt[i] : 0;
    if (i < N) invsqrt[i] = rsqrtf((float)(v + 1));   // +1: self-loop
    sd[t] = v;
    __syncthreads();
#pragma unroll
    for (int s = 128; s > 0; s >>= 1) {
        if (t < s) sd[t] += sd[t + s];
        __syncthreads();
    }
    if (t == 0) blocksums[blockIdx.x] = sd[0];
}

__global__ __launch_bounds__(1024) void k_scan_blocks(int* blocksums, int NB) {
    __shared__ int s[1024];
    int t = threadIdx.x;
    int v = (t < NB) ? blocksums[t] : 0;
    s[t] = v;
    __syncthreads();
    for (int off = 1; off < 1024; off <<= 1) {
        int x = (t >= off) ? s[t - off] : 0;
        __syncthreads();
        s[t] += x;
        __syncthreads();
    }
    if (t < NB) blocksums[t] = s[t] - v;   // exclusive
}

__global__ __launch_bounds__(256) void k_rowstart(const int* __restrict__ degcnt,
                                                  const int* __restrict__ blocksums,
                                                  int* __restrict__ rowstart,
                                                  int* __restrict__ rowwork, int N, int E) {
    __shared__ int s[256];
    int t = threadIdx.x;
    int i = blockIdx.x * 256 + t;
    int v = (i < N) ? degcnt[i] : 0;
    s[t] = v;
    __syncthreads();
    for (int off = 1; off < 256; off <<= 1) {
        int x = (t >= off) ? s[t - off] : 0;
        __syncthreads();
        s[t] += x;
        __syncthreads();
    }
    if (i < N) {
        int e = s[t] - v + blocksums[blockIdx.x];
        rowstart[i] = e;
        rowwork[i] = e;
    }
    if (blockIdx.x == 0 && t == 0) rowstart[N] = E;
}

__global__ __launch_bounds__(256) void k_fill(const int* __restrict__ src,
                                              const int* __restrict__ dst, int E,
                                              const float* __restrict__ invsqrt,
                                              int* __restrict__ rowwork,
                                              uint2* __restrict__ csr_sw) {
    int i = blockIdx.x * 256 + threadIdx.x;
    if (i < E) {
        int s = src[i], d = dst[i];
        int pos = atomicAdd(&rowwork[d], 1);
        csr_sw[pos] = make_uint2((unsigned int)s, __float_as_uint(invsqrt[s]));
    }
}

// ---------------- weight prep: transpose + bf16 hi/lo split ----------------
// w1t[c][k] (c<128,k<256); w2t[c][k] (c<128,k<128; c<64 -> Wmu col, else Wls col)

__global__ __launch_bounds__(256) void k_wprep(const float* __restrict__ W1,
                                               const float* __restrict__ Wmu,
                                               const float* __restrict__ Wls,
                                               unsigned short* __restrict__ w1t_hi,
                                               unsigned short* __restrict__ w1t_lo,
                                               unsigned short* __restrict__ w2t_hi,
                                               unsigned short* __restrict__ w2t_lo) {
    int i = blockIdx.x * 256 + threadIdx.x;
    if (i < 256 * 128) {
        int k = i >> 7, c = i & 127;
        float w = W1[k * 128 + c];
        unsigned short hi = f2bf(w);
        unsigned short lo = f2bf(w - bf2f(hi));
        w1t_hi[c * 256 + k] = hi;
        w1t_lo[c * 256 + k] = lo;
    } else {
        int j = i - 256 * 128;
        if (j < 128 * 128) {
            int k = j >> 7, c = j & 127;
            float w = (c < 64) ? Wmu[k * 64 + c] : Wls[k * 64 + (c - 64)];
            unsigned short hi = f2bf(w);
            unsigned short lo = f2bf(w - bf2f(hi));
            w2t_hi[c * 128 + k] = hi;
            w2t_lo[c * 128 + k] = lo;
        }
    }
}

// ---------------- MFMA GEMM: A[N,KTOT] f32 (split on the fly) @ B^T hi/lo bf16 ----------------
// Tile 128 rows x 128 cols, 4 waves in 2x2, each wave 64x64 (4 m-frags x 4 n-frags).
// 3 products: Ahi*Bhi + Ahi*Blo + Alo*Bhi (lo*lo dropped, ~2^-18 rel).
// LDS frag layout: [row][k] bf16, row stride 40 ushorts (80 B, 16B-aligned, bank-spread).
// Frag for lane l: row/col = base + (l&15), k-chunk = (l>>4)*8 -> one b128 read.
// C/D (m89-verified): col = lane&15, row = (lane>>4)*4 + reg.
// MODE 1: store f16 bits to H1 ushort[N][128]. MODE 2: +bias, f32 to omu/ols.

template <int KTOT, int MODE>
__global__ __launch_bounds__(256) void k_gemm_mfma(const float* __restrict__ A,
                                                   const unsigned short* __restrict__ Bh,
                                                   const unsigned short* __restrict__ Bl,
                                                   const float* __restrict__ bmu,
                                                   const float* __restrict__ bls,
                                                   unsigned short* __restrict__ o16,
                                                   float* __restrict__ omu,
                                                   float* __restrict__ ols, int N) {
    __shared__ __align__(16) unsigned short As_hi[128 * 40];
    __shared__ __align__(16) unsigned short As_lo[128 * 40];
    __shared__ __align__(16) unsigned short Bs_hi[128 * 40];
    __shared__ __align__(16) unsigned short Bs_lo[128 * 40];

    int t = threadIdx.x;
    int l = t & 63;
    int w = t >> 6;
    int wm = (w >> 1) * 64;
    int wn = (w & 1) * 64;
    int lr = l & 15;        // frag row/col
    int lc = l >> 4;        // k-chunk (0..3), 8 bf16 each
    int row0 = blockIdx.x * 128;

    f32x4 acc[4][4];
#pragma unroll
    for (int a = 0; a < 4; a++)
#pragma unroll
        for (int b = 0; b < 4; b++) acc[a][b] = (f32x4){0.f, 0.f, 0.f, 0.f};

    for (int k0 = 0; k0 < KTOT; k0 += 32) {
        // ---- stage A: 128 rows x 32 k f32 -> hi/lo bf16 (1024 float4, 4/thread) ----
#pragma unroll
        for (int it = 0; it < 4; it++) {
            int idx = t + 256 * it;
            int rr = idx >> 3, kq = idx & 7;
            int grow = row0 + rr;
            float4 v = make_float4(0.f, 0.f, 0.f, 0.f);
            if (grow < N) v = *(const float4*)(A + (size_t)grow * KTOT + k0 + kq * 4);
            ushort4 h, lo;
            h.x = f2bf(v.x); lo.x = f2bf(v.x - bf2f(h.x));
            h.y = f2bf(v.y); lo.y = f2bf(v.y - bf2f(h.y));
            h.z = f2bf(v.z); lo.z = f2bf(v.z - bf2f(h.z));
            h.w = f2bf(v.w); lo.w = f2bf(v.w - bf2f(h.w));
            *(ushort4*)&As_hi[rr * 40 + kq * 4] = h;
            *(ushort4*)&As_lo[rr * 40 + kq * 4] = lo;
        }
        // ---- stage B: 128 cols x 32 k bf16 from pre-split B^T (512 16B chunks x2, 2/thread each) ----
#pragma unroll
        for (int it = 0; it < 2; it++) {
            int idx = t + 256 * it;
            int col = idx >> 2, ck = idx & 3;
            uint4 vh = *(const uint4*)(Bh + (size_t)col * KTOT + k0 + ck * 8);
            uint4 vl = *(const uint4*)(Bl + (size_t)col * KTOT + k0 + ck * 8);
            *(uint4*)&Bs_hi[col * 40 + ck * 8] = vh;
            *(uint4*)&Bs_lo[col * 40 + ck * 8] = vl;
        }
        __syncthreads();

        bf16x8 ah[4], al[4];
#pragma unroll
        for (int mf = 0; mf < 4; mf++) {
            int r = wm + mf * 16 + lr;
            ah[mf] = *(bf16x8*)&As_hi[r * 40 + lc * 8];
            al[mf] = *(bf16x8*)&As_lo[r * 40 + lc * 8];
        }
#pragma unroll
        for (int nf = 0; nf < 4; nf++) {
            int c = wn + nf * 16 + lr;
            bf16x8 bh = *(bf16x8*)&Bs_hi[c * 40 + lc * 8];
            bf16x8 bl = *(bf16x8*)&Bs_lo[c * 40 + lc * 8];
#pragma unroll
            for (int mf = 0; mf < 4; mf++)
                acc[mf][nf] = __builtin_amdgcn_mfma_f32_16x16x32_bf16(ah[mf], bh, acc[mf][nf], 0, 0, 0);
#pragma unroll
            for (int mf = 0; mf < 4; mf++)
                acc[mf][nf] = __builtin_amdgcn_mfma_f32_16x16x32_bf16(ah[mf], bl, acc[mf][nf], 0, 0, 0);
#pragma unroll
            for (int mf = 0; mf < 4; mf++)
                acc[mf][nf] = __builtin_amdgcn_mfma_f32_16x16x32_bf16(al[mf], bh, acc[mf][nf], 0, 0, 0);
        }
        __syncthreads();
    }

    // ---- store ----
#pragma unroll
    for (int mf = 0; mf < 4; mf++) {
#pragma unroll
        for (int nf = 0; nf < 4; nf++) {
            int col = wn + nf * 16 + lr;
#pragma unroll
            for (int r = 0; r < 4; r++) {
                int row = row0 + wm + mf * 16 + lc * 4 + r;
                if (row < N) {
                    float v = acc[mf][nf][r];
                    if (MODE == 1) {
                        o16[(size_t)row * 128 + col] = f2h_bits(v);
                    } else {
                        if (col < 64) omu[(size_t)row * 64 + col] = v + bmu[col];
                        else          ols[(size_t)row * 64 + (col - 64)] = v + bls[col - 64];
                    }
                }
            }
        }
    }
}

// ---------------- Aggregation over f16x2 table ----------------
// out[i] = isq_i*(sum_e w_e*tbl[s_e] + isq_i*tbl[i]); MODE1: +bias, relu, f16 out; MODE0: f32 out.

template <int MODE>
__global__ __launch_bounds__(256, 8) void k_agg(const unsigned int* __restrict__ tbl,
                                                const float* __restrict__ invsqrt,
                                                const int* __restrict__ rowstart,
                                                const uint2* __restrict__ csr,
                                                const float* __restrict__ bias,
                                                unsigned int* __restrict__ out16,
                                                float2* __restrict__ out32, int N) {
    int node = blockIdx.x * 4 + (threadIdx.x >> 6);
    int t = threadIdx.x & 63;
    if (node >= N) return;
    int start = rowstart[node], end = rowstart[node + 1];
    float isq = invsqrt[node];
    float2 v = unpack_h2(tbl[(size_t)node * 64 + t]);
    float aL = isq * v.x, aH = isq * v.y;   // self term (outer isq applied at end)
    for (int base = start; base < end; base += 64) {
        int cnt = end - base;
        if (cnt > 64) cnt = 64;
        uint2 e = make_uint2(0u, 0u);
        if (t < cnt) e = csr[base + t];
        int j = 0;
        for (; j + 2 <= cnt; j += 2) {
            int s0 = __shfl((int)e.x, j);
            float w0 = __int_as_float(__shfl((int)e.y, j));
            int s1 = __shfl((int)e.x, j + 1);
            float w1 = __int_as_float(__shfl((int)e.y, j + 1));
            float2 f0 = unpack_h2(tbl[(size_t)s0 * 64 + t]);
            float2 f1 = unpack_h2(tbl[(size_t)s1 * 64 + t]);
            aL = fmaf(w0, f0.x, aL);
            aH = fmaf(w0, f0.y, aH);
            aL = fmaf(w1, f1.x, aL);
            aH = fmaf(w1, f1.y, aH);
        }
        if (j < cnt) {
            int s0 = __shfl((int)e.x, j);
            float w0 = __int_as_float(__shfl((int)e.y, j));
            float2 f0 = unpack_h2(tbl[(size_t)s0 * 64 + t]);
            aL = fmaf(w0, f0.x, aL);
            aH = fmaf(w0, f0.y, aH);
        }
    }
    aL *= isq;
    aH *= isq;
    if (MODE == 1) {
        float2 b = ((const float2*)bias)[t];
        aL = fmaxf(aL + b.x, 0.f);
        aH = fmaxf(aH + b.y, 0.f);
        out16[(size_t)node * 64 + t] = pack_h2(aL, aH);
    } else {
        out32[(size_t)node * 64 + t] = make_float2(aL, aH);
    }
}

// ---------------- launch ----------------

extern "C" void kernel_launch(void* const* d_in, const int* in_sizes, int n_in,
                              void* d_out, int out_size, void* d_ws, size_t ws_size,
                              hipStream_t stream) {
    const float* x   = (const float*)d_in[0];
    const int*   ei  = (const int*)d_in[1];
    const float* W1  = (const float*)d_in[2];
    const float* b1  = (const float*)d_in[3];
    const float* Wmu = (const float*)d_in[4];
    const float* bmu = (const float*)d_in[5];
    const float* Wls = (const float*)d_in[6];
    const float* bls = (const float*)d_in[7];

    int N = in_sizes[0] / 256;
    int E = in_sizes[1] / 2;
    const int* src = ei;
    const int* dst = ei + E;
    float* omu = (float*)d_out;
    float* ols = omu + (size_t)N * 64;

    char* w = (char*)d_ws;
    size_t off = 0;
    auto alloc = [&](size_t bytes) -> char* {
        char* p = w + off;
        off = (off + bytes + 255) & ~(size_t)255;
        return p;
    };
    int*            degcnt    = (int*)alloc((size_t)N * 4);
    float*          invsqrt   = (float*)alloc((size_t)N * 4);
    int*            rowstart  = (int*)alloc((size_t)(N + 1) * 4);
    int*            rowwork   = (int*)alloc((size_t)N * 4);
    int*            blocksums = (int*)alloc(4096);
    uint2*          csr_sw    = (uint2*)alloc((size_t)E * 8);
    unsigned int*   H1f16     = (unsigned int*)alloc((size_t)N * 64 * 4);  // x@W1, f16x2
    unsigned int*   Hf16      = (unsigned int*)alloc((size_t)N * 64 * 4);  // relu(agg1), f16x2
    float*          G2        = (float*)alloc((size_t)N * 128 * 4);        // agg2 out, f32
    unsigned short* w1t_hi    = (unsigned short*)alloc(128 * 256 * 2);
    unsigned short* w1t_lo    = (unsigned short*)alloc(128 * 256 * 2);
    unsigned short* w2t_hi    = (unsigned short*)alloc(128 * 128 * 2);
    unsigned short* w2t_lo    = (unsigned short*)alloc(128 * 128 * 2);

    int NB = (N + 255) / 256;

    hipMemsetAsync(degcnt, 0, (size_t)N * 4, stream);
    k_wprep<<<192, 256, 0, stream>>>(W1, Wmu, Wls, w1t_hi, w1t_lo, w2t_hi, w2t_lo);
    k_hist<<<(E + 255) / 256, 256, 0, stream>>>(dst, E, degcnt);
    k_deg_finalize<<<NB, 256, 0, stream>>>(degcnt, invsqrt, blocksums, N);
    k_scan_blocks<<<1, 1024, 0, stream>>>(blocksums, NB);
    k_rowstart<<<NB, 256, 0, stream>>>(degcnt, blocksums, rowstart, rowwork, N, E);
    k_fill<<<(E + 255) / 256, 256, 0, stream>>>(src, dst, E, invsqrt, rowwork, csr_sw);

    int GB = (N + 127) / 128;
    k_gemm_mfma<256, 1><<<GB, 256, 0, stream>>>(x, w1t_hi, w1t_lo, nullptr, nullptr,
                                                (unsigned short*)H1f16, nullptr, nullptr, N);
    k_agg<1><<<(N + 3) / 4, 256, 0, stream>>>(H1f16, invsqrt, rowstart, csr_sw, b1,
                                              Hf16, nullptr, N);
    k_agg<0><<<(N + 3) / 4, 256, 0, stream>>>(Hf16, invsqrt, rowstart, csr_sw, nullptr,
                                              nullptr, (float2*)G2, N);
    k_gemm_mfma<128, 2><<<GB, 256, 0, stream>>>(G2, w2t_hi, w2t_lo, bmu, bls,
                                                nullptr, omu, ols, N);
}